// Round 8
// baseline (183.178 us; speedup 1.0000x reference)
//
#include <hip/hip_runtime.h>
#include <stdint.h>

// ---------------------------------------------------------------------------
// CommNetActor fused forward v8 — bf16x3 split-precision MFMA (gfx950).
//
//  R7 post-mortem: MFMA 72us (floor 62), VALU 71us, but ~50% of wall neither
//  pipe issues -> latency/barrier stalls at 3 waves/SIMD. v8 targets 4
//  blocks/CU (16 waves/CU) by capping the register peak at 32 acc:
//   - cl4 restructured: band0 (rows 0-31) -> barrier -> flush res0 into X
//     rows 0-31 WHILE band1 reads rows 32-63 (disjoint) -> barrier -> flush
//     res1. Never more than a1+a2=32 acc live (v7 held 64).
//   - std-layer B prefetch depth 3->2 (-16 arch regs; TLP covers latency).
//   - __launch_bounds__(256, 4): unified 128 = ~96 arch + 32 acc.
//   - divisions -> v_rcp_f32 (sigmoid epilogue had 32 ~10-inst divs/thread).
//  Everything else = v7: distinct 32-col wave ownership (B fetched once per
//  block), 33.8 KB LDS, fused comm-in-accumulator cl4, atomic dec reduce.
//  MFMA 32x32x16_bf16, D layout col=lane&31, row=(r&3)+8*(r>>2)+4*(lane>>5).
// ---------------------------------------------------------------------------

typedef __attribute__((ext_vector_type(4)))  float f32x4;
typedef __attribute__((ext_vector_type(16))) float f32x16;
typedef __attribute__((ext_vector_type(8)))  short bf16x8;
typedef __attribute__((ext_vector_type(4)))  short bf16x4;

#define WS_HALF 106496
#define SEG_ENC 0
#define SEG_FC1 8192
#define SEG_FC2 24576
#define SEG_FC3 40960
#define SEG_W1  57344
#define SEG_W2  73728
#define SEG_DEC 90112

#define MFMA(a, b, c) __builtin_amdgcn_mfma_f32_32x32x16_bf16((a), (b), (c), 0, 0, 0)

__device__ __forceinline__ unsigned short bf16_rn(float f) {
  union { float f; uint32_t u; } v; v.f = f;
  uint32_t u = v.u;
  return (unsigned short)((u + 0x7FFFu + ((u >> 16) & 1u)) >> 16);
}
__device__ __forceinline__ float bf16_f32(unsigned short h) {
  union { uint32_t u; float f; } v; v.u = ((uint32_t)h) << 16;
  return v.f;
}
// hi = round-nearest bf16; lo = truncated bf16 of residual.
__device__ __forceinline__ void split_hl(float v, short& h, short& l) {
  unsigned short hh = bf16_rn(v);
  h = (short)hh;
  union { float f; uint32_t u; } c; c.f = v - bf16_f32(hh);
  l = (short)(c.u >> 16);
}
__device__ __forceinline__ f32x16 zero16() {
  f32x16 v;
#pragma unroll
  for (int i = 0; i < 16; ++i) v[i] = 0.0f;
  return v;
}
// swizzled bf16 index: pitch 128, 16B groups XOR'd by row&15
__device__ __forceinline__ int xswz(int row, int g) {
  return row * 128 + ((g ^ (row & 15)) << 3);
}
// barrier draining LDS ops only — register-bound global loads stay in flight
__device__ __forceinline__ void barrier_lds() {
  asm volatile("s_waitcnt lgkmcnt(0)\n\ts_barrier" ::: "memory");
}

// ---------------------------------------------------------------------------
// Weight prep (layout unchanged): fragment f = kc*nbN + nb,
//   value = W[kc*16 + (lane>>5)*8 + j][nb*32 + (lane&31)]
// cl4 split into W1 = Wtop - 0.25*Wbot and W2 = 0.25*Wbot. dec padded N16->32.
// ---------------------------------------------------------------------------
__global__ void prep_weights(const float* __restrict__ enc_w, const float* __restrict__ fc1_w,
                             const float* __restrict__ fc2_w, const float* __restrict__ fc3_w,
                             const float* __restrict__ cl4_w, const float* __restrict__ dec_w,
                             unsigned short* __restrict__ ws) {
  int idx = blockIdx.x * 256 + threadIdx.x;
  if (idx >= WS_HALF) return;
  const float* W; int base, N, nbN, mode;
  if      (idx <  8192) { W = enc_w; base = SEG_ENC; N = 128; nbN = 4; mode = 0; }
  else if (idx < 24576) { W = fc1_w; base = SEG_FC1; N = 128; nbN = 4; mode = 0; }
  else if (idx < 40960) { W = fc2_w; base = SEG_FC2; N = 128; nbN = 4; mode = 0; }
  else if (idx < 57344) { W = fc3_w; base = SEG_FC3; N = 128; nbN = 4; mode = 0; }
  else if (idx < 73728) { W = cl4_w; base = SEG_W1;  N = 128; nbN = 4; mode = 1; }
  else if (idx < 90112) { W = cl4_w; base = SEG_W2;  N = 128; nbN = 4; mode = 2; }
  else                  { W = dec_w; base = SEG_DEC; N = 16;  nbN = 1; mode = 0; }
  int local = idx - base;
  int j    = local & 7;
  int lane = (local >> 3) & 63;
  int frag = local >> 9;
  int nb = frag % nbN;
  int kc = frag / nbN;
  int k = kc * 16 + ((lane >> 5) << 3) + j;
  int n = nb * 32 + (lane & 31);
  float wv;
  if (mode == 0)      wv = (n < N) ? W[k * N + n] : 0.0f;
  else if (mode == 1) wv = W[k * 128 + n] - 0.25f * W[(k + 128) * 128 + n];
  else                wv = 0.25f * W[(k + 128) * 128 + n];
  unsigned short hi = bf16_rn(wv);
  ws[idx]           = hi;
  ws[WS_HALF + idx] = bf16_rn(wv - bf16_f32(hi));
}

// ---------------------------------------------------------------------------
// Standard layer: X[64][K] @ W[K][128] + b, act, in-place into Xhi/Xlo.
// Wave w owns cols w*32..+31 (distinct B, fetched once per block), reads all
// 64 rows (acc0 rows 0-31, acc1 rows 32-63). B depth-2 prefetch from L2.
// ---------------------------------------------------------------------------
template <int KC, int ACT>
__device__ __forceinline__ void layer_std(short* __restrict__ Xhi, short* __restrict__ Xlo,
                                          const unsigned short* __restrict__ whi,
                                          const unsigned short* __restrict__ wlo,
                                          const float* __restrict__ bias,
                                          int lr, int lh, int w) {
  const int l = lh * 32 + lr;
  f32x16 acc0 = zero16(), acc1 = zero16();
  const unsigned short* bh = whi + w * 512 + l * 8;
  const unsigned short* bl = wlo + w * 512 + l * 8;
  bf16x8 Bh[2], Bl[2];
  Bh[0] = *(const bf16x8*)(bh);
  Bl[0] = *(const bf16x8*)(bl);
  barrier_lds();   // X from previous phase visible (B loads stay in flight)
#pragma unroll
  for (int kc = 0; kc < KC; ++kc) {
    const int cur = kc & 1;
    if (kc + 1 < KC) {
      Bh[cur ^ 1] = *(const bf16x8*)(bh + (kc + 1) * 2048);
      Bl[cur ^ 1] = *(const bf16x8*)(bl + (kc + 1) * 2048);
    }
    const int g = kc * 2 + lh;
    const int xi0 = xswz(lr, g), xi1 = xswz(lr + 32, g);
    const bf16x8 ah0 = *(const bf16x8*)&Xhi[xi0];
    const bf16x8 al0 = *(const bf16x8*)&Xlo[xi0];
    const bf16x8 ah1 = *(const bf16x8*)&Xhi[xi1];
    const bf16x8 al1 = *(const bf16x8*)&Xlo[xi1];
    acc0 = MFMA(ah0, Bh[cur], acc0);
    acc1 = MFMA(ah1, Bh[cur], acc1);
    acc0 = MFMA(al0, Bh[cur], acc0);
    acc1 = MFMA(al1, Bh[cur], acc1);
    acc0 = MFMA(ah0, Bl[cur], acc0);
    acc1 = MFMA(ah1, Bl[cur], acc1);
  }
  barrier_lds();   // all waves done reading X -> in-place write safe
  const int col = w * 32 + lr;
  const float bv = bias[col];
  const int cg = col >> 3, co = col & 7;
#pragma unroll
  for (int mb = 0; mb < 2; ++mb) {
    const f32x16 a = mb ? acc1 : acc0;
#pragma unroll
    for (int r = 0; r < 16; ++r) {
      const int orow = mb * 32 + (r & 3) + 8 * (r >> 2) + 4 * lh;
      float v = a[r] + bv;
      if (ACT == 0)      v = __builtin_amdgcn_rcpf(1.0f + __expf(-v));  // sigmoid
      else if (ACT == 1) v = fmaxf(v, 0.0f);                            // relu
      short h, lo2;
      split_hl(v, h, lo2);
      const int idx = orow * 128 + ((cg ^ (orow & 15)) << 3) + co;
      Xhi[idx] = h;
      Xlo[idx] = lo2;
    }
  }
}

// ---------------------------------------------------------------------------
// cl4 band MB (rows MB*32..+31, cols w*32..+31): a1 = H3@W1, a2 = H3@W2.
// H4 = a1[r] + T_q + b, T_q = sum of a2[4q..4q+3] (4 agent rows of one batch
// sit in 4 consecutive accumulator regs of the same lane). Acc peak = 32.
// ---------------------------------------------------------------------------
template <int MB>
__device__ __forceinline__ f32x16 cl4_band(const short* __restrict__ Xhi,
                                           const short* __restrict__ Xlo,
                                           const unsigned short* __restrict__ whi,
                                           const unsigned short* __restrict__ wlo,
                                           const float* __restrict__ cl4_b,
                                           int lr, int lh, int w) {
  const int l = lh * 32 + lr;
  f32x16 a1 = zero16(), a2 = zero16();
  const unsigned short* b1h = whi + SEG_W1 + w * 512 + l * 8;
  const unsigned short* b1l = wlo + SEG_W1 + w * 512 + l * 8;
  const unsigned short* b2h = whi + SEG_W2 + w * 512 + l * 8;
  const unsigned short* b2l = wlo + SEG_W2 + w * 512 + l * 8;
  bf16x8 B1h[2], B1l[2], B2h[2], B2l[2];
  B1h[0] = *(const bf16x8*)(b1h);
  B1l[0] = *(const bf16x8*)(b1l);
  B2h[0] = *(const bf16x8*)(b2h);
  B2l[0] = *(const bf16x8*)(b2l);
#pragma unroll
  for (int kc = 0; kc < 8; ++kc) {
    const int cur = kc & 1;
    if (kc < 7) {
      const int nx = cur ^ 1;
      B1h[nx] = *(const bf16x8*)(b1h + (kc + 1) * 2048);
      B1l[nx] = *(const bf16x8*)(b1l + (kc + 1) * 2048);
      B2h[nx] = *(const bf16x8*)(b2h + (kc + 1) * 2048);
      B2l[nx] = *(const bf16x8*)(b2l + (kc + 1) * 2048);
    }
    const int xi = xswz(MB * 32 + lr, kc * 2 + lh);
    const bf16x8 ah = *(const bf16x8*)&Xhi[xi];
    const bf16x8 al = *(const bf16x8*)&Xlo[xi];
    a1 = MFMA(ah, B1h[cur], a1);
    a2 = MFMA(ah, B2h[cur], a2);
    a1 = MFMA(al, B1h[cur], a1);
    a2 = MFMA(al, B2h[cur], a2);
    a1 = MFMA(ah, B1l[cur], a1);
    a2 = MFMA(ah, B2l[cur], a2);
  }
  const float bv = cl4_b[w * 32 + lr];
  f32x16 res;
#pragma unroll
  for (int q = 0; q < 4; ++q) {
    const float T = (a2[4 * q] + a2[4 * q + 1]) + (a2[4 * q + 2] + a2[4 * q + 3]);
#pragma unroll
    for (int rr = 0; rr < 4; ++rr) res[4 * q + rr] = a1[4 * q + rr] + T + bv;
  }
  return res;
}

// write one band's H4 result into X rows MB*32..+31 (split hi/lo, swizzled)
template <int MB>
__device__ __forceinline__ void cl4_write(short* __restrict__ Xhi, short* __restrict__ Xlo,
                                          const f32x16& rs, int lr, int lh, int w) {
  const int col = w * 32 + lr;
  const int cg = col >> 3, co = col & 7;
#pragma unroll
  for (int r = 0; r < 16; ++r) {
    const int orow = MB * 32 + (r & 3) + 8 * (r >> 2) + 4 * lh;
    short h, lo2;
    split_hl(rs[r], h, lo2);
    const int idx = orow * 128 + ((cg ^ (orow & 15)) << 3) + co;
    Xhi[idx] = h;
    Xlo[idx] = lo2;
  }
}

// ---------------------------------------------------------------------------
__global__ __launch_bounds__(256, 4)
void commnet_fwd(const float* __restrict__ O,
                 const float* __restrict__ enc_b, const float* __restrict__ fc1_b,
                 const float* __restrict__ fc2_b, const float* __restrict__ fc3_b,
                 const float* __restrict__ cl4_b, const float* __restrict__ dec_b,
                 const unsigned short* __restrict__ ws, float* __restrict__ out) {
  __shared__ __attribute__((aligned(16))) short Xhi[64 * 128];  // 16 KB
  __shared__ __attribute__((aligned(16))) short Xlo[64 * 128];  // 16 KB
  __shared__ __attribute__((aligned(16))) float Pbuf[256];      //  1 KB

  const int tid = threadIdx.x;
  const int l = tid & 63, w = tid >> 6;
  const int lr = l & 31, lh = l >> 5;

  Pbuf[tid] = 0.0f;   // dec partial accumulator (one element per thread)

  // ---- stage O [64 x 64] f32 -> split -> swizzled Xhi/Xlo groups 0..7 ----
  {
    const f32x4* Og = (const f32x4*)(O + (long)blockIdx.x * 4096);
#pragma unroll
    for (int it = 0; it < 4; ++it) {
      const int i = it * 256 + tid;       // 0..1023
      const int row = i >> 4;
      const int c4 = (i & 15) << 2;
      f32x4 v = Og[i];
      bf16x4 hv, lv;
#pragma unroll
      for (int j = 0; j < 4; ++j) {
        short hh, ll;
        split_hl(v[j], hh, ll);
        hv[j] = hh; lv[j] = ll;
      }
      const int bi = row * 128 + (((c4 >> 3) ^ (row & 15)) << 3) + (c4 & 7);
      *(bf16x4*)&Xhi[bi] = hv;
      *(bf16x4*)&Xlo[bi] = lv;
    }
  }

  const unsigned short* whi = ws;
  const unsigned short* wlo = ws + WS_HALF;

  layer_std<4, 0>(Xhi, Xlo, whi + SEG_ENC, wlo + SEG_ENC, enc_b, lr, lh, w);
  layer_std<8, 1>(Xhi, Xlo, whi + SEG_FC1, wlo + SEG_FC1, fc1_b, lr, lh, w);
  layer_std<8, 1>(Xhi, Xlo, whi + SEG_FC2, wlo + SEG_FC2, fc2_b, lr, lh, w);
  layer_std<8, 1>(Xhi, Xlo, whi + SEG_FC3, wlo + SEG_FC3, fc3_b, lr, lh, w);

  // ---- cl4: band0 -> flush res0 -> band1 -> flush res1 (acc peak = 32) ----
  barrier_lds();   // H3 (fc3 epilogue) visible
  {
    const f32x16 res0 = cl4_band<0>(Xhi, Xlo, whi, wlo, cl4_b, lr, lh, w);
    barrier_lds();  // all waves done reading rows 0-31
    cl4_write<0>(Xhi, Xlo, res0, lr, lh, w);   // rows 0-31, disjoint from band1 reads
  }
  {
    const f32x16 res1 = cl4_band<1>(Xhi, Xlo, whi, wlo, cl4_b, lr, lh, w);
    barrier_lds();  // all waves done reading rows 32-63 (res0 writes drained too)
    cl4_write<1>(Xhi, Xlo, res1, lr, lh, w);
  }
  barrier_lds();   // H4 fully visible

  // ---- dec: [16 x 512] @ dec_w(pad32); 8 kc per wave; LDS atomic reduce ----
  {
    f32x16 dacc = zero16();
    const unsigned short* bh = whi + SEG_DEC + (w * 8) * 512 + l * 8;
    const unsigned short* bl = wlo + SEG_DEC + (w * 8) * 512 + l * 8;
    bf16x8 Bh[2], Bl[2];
    Bh[0] = *(const bf16x8*)(bh);
    Bl[0] = *(const bf16x8*)(bl);
#pragma unroll
    for (int kq = 0; kq < 8; ++kq) {
      const int cur = kq & 1;
      if (kq < 7) {
        Bh[cur ^ 1] = *(const bf16x8*)(bh + (kq + 1) * 512);
        Bl[cur ^ 1] = *(const bf16x8*)(bl + (kq + 1) * 512);
      }
      const int kcg = w * 8 + kq;          // global k-chunk 0..31
      const int k0 = kcg * 16 + lh * 8;    // 0..504
      const int agent = k0 >> 7;
      const int d0 = k0 & 127;
      const int row = (lr & 15) * 4 + agent;   // batch (dup for lr>=16), agent
      const int xi = xswz(row, d0 >> 3);
      const bf16x8 ah = *(const bf16x8*)&Xhi[xi];
      const bf16x8 al = *(const bf16x8*)&Xlo[xi];
      dacc = MFMA(ah, Bh[cur], dacc);
      dacc = MFMA(al, Bh[cur], dacc);
      dacc = MFMA(ah, Bl[cur], dacc);
    }
    if (lr < 16) {   // cols 16..31 are zero-pad; D rows 16..31 are dup batches
#pragma unroll
      for (int r = 0; r < 8; ++r) {
        const int batch = (r & 3) + 8 * (r >> 2) + 4 * lh;   // 0..15
        atomicAdd(&Pbuf[batch * 16 + lr], dacc[r]);
      }
    }
  }
  barrier_lds();   // partials complete

  // ---- + bias, softmax over 16 actions, coalesced store ----
  {
    const int c = tid & 15;
    float v = Pbuf[tid] + dec_b[c];
    float m = v;
#pragma unroll
    for (int mk = 1; mk < 16; mk <<= 1) m = fmaxf(m, __shfl_xor(m, mk, 16));
    const float e = __expf(v - m);
    float s = e;
#pragma unroll
    for (int mk = 1; mk < 16; mk <<= 1) s += __shfl_xor(s, mk, 16);
    out[(long)blockIdx.x * 256 + tid] = e * __builtin_amdgcn_rcpf(s);
  }
}

// ---------------------------------------------------------------------------
extern "C" void kernel_launch(void* const* d_in, const int* in_sizes, int n_in,
                              void* d_out, int out_size, void* d_ws, size_t ws_size,
                              hipStream_t stream) {
  (void)n_in; (void)out_size; (void)ws_size;  // needs ws_size >= 425,984 B
  const float* O     = (const float*)d_in[0];
  const float* enc_w = (const float*)d_in[1];
  const float* enc_b = (const float*)d_in[2];
  const float* fc1_w = (const float*)d_in[3];
  const float* fc1_b = (const float*)d_in[4];
  const float* fc2_w = (const float*)d_in[5];
  const float* fc2_b = (const float*)d_in[6];
  const float* fc3_w = (const float*)d_in[7];
  const float* fc3_b = (const float*)d_in[8];
  const float* cl4_w = (const float*)d_in[9];
  const float* cl4_b = (const float*)d_in[10];
  const float* dec_w = (const float*)d_in[11];
  const float* dec_b = (const float*)d_in[12];
  unsigned short* wsb = (unsigned short*)d_ws;

  prep_weights<<<(WS_HALF + 255) / 256, 256, 0, stream>>>(enc_w, fc1_w, fc2_w, fc3_w,
                                                          cl4_w, dec_w, wsb);
  const int rows   = in_sizes[0] / 64;   // B*A = 262144
  const int blocks = rows / 64;          // 4096
  commnet_fwd<<<blocks, 256, 0, stream>>>(O, enc_b, fc1_b, fc2_b, fc3_b, cl4_b,
                                          dec_b, wsb, (float*)d_out);
}

// Round 10
// 181.770 us; speedup vs baseline: 1.0077x; 1.0077x over previous
//
#include <hip/hip_runtime.h>
#include <stdint.h>

// ---------------------------------------------------------------------------
// CommNetActor fused forward v10 — bf16x3 split-precision MFMA (gfx950).
//
//  v10 = v9 + Pbuf init fix. R9 post-mortem: v9's operand-swap math verified
//  sound; failure was Pbuf[272] zeroed by `if(tid<272) Pbuf[tid]=0` with only
//  256 threads -> elements 256..270 (batch 15, actions 1..15) kept stale LDS
//  garbage from the previous block on the CU. absmax 0.336 on every 16th
//  batch. Fix: 16 extra zeros from threads 0..15.
//
//  Structure (v9): operand-swapped MFMA -> D^T = W^T @ X^T:
//   - lane&31 = output/X ROW, reg-quads = 4 consecutive output cols ->
//     epilogue = 16x ds_write_b64 per thread/layer (was 64x ds_write_b16);
//     LDS write pipe ~61us -> ~15us per CU.
//   - bias per-reg: 4x global_load_dwordx4 per layer, hidden under K-loop.
//   - cl4 comm: agents = adjacent lanes -> T via shfl_xor(1)+shfl_xor(2).
//   - dec: lane = batch, regs = actions; partials via LDS atomicAdd, pitch 17.
//  Config = v7 (best): (256,3), depth-3 B prefetch, 33.9KB LDS, distinct
//  32-col wave ownership (B fetched once per block).
//  MFMA 32x32x16_bf16, C/D: col=lane&31, row=(r&3)+8*(r>>2)+4*(lane>>5).
// ---------------------------------------------------------------------------

typedef __attribute__((ext_vector_type(4)))  float f32x4;
typedef __attribute__((ext_vector_type(16))) float f32x16;
typedef __attribute__((ext_vector_type(8)))  short bf16x8;
typedef __attribute__((ext_vector_type(4)))  short bf16x4;

#define WS_HALF 106496
#define SEG_ENC 0
#define SEG_FC1 8192
#define SEG_FC2 24576
#define SEG_FC3 40960
#define SEG_W1  57344
#define SEG_W2  73728
#define SEG_DEC 90112

#define MFMA(a, b, c) __builtin_amdgcn_mfma_f32_32x32x16_bf16((a), (b), (c), 0, 0, 0)

__device__ __forceinline__ unsigned short bf16_rn(float f) {
  union { float f; uint32_t u; } v; v.f = f;
  uint32_t u = v.u;
  return (unsigned short)((u + 0x7FFFu + ((u >> 16) & 1u)) >> 16);
}
__device__ __forceinline__ float bf16_f32(unsigned short h) {
  union { uint32_t u; float f; } v; v.u = ((uint32_t)h) << 16;
  return v.f;
}
// hi = round-nearest bf16; lo = truncated bf16 of residual.
__device__ __forceinline__ void split_hl(float v, short& h, short& l) {
  unsigned short hh = bf16_rn(v);
  h = (short)hh;
  union { float f; uint32_t u; } c; c.f = v - bf16_f32(hh);
  l = (short)(c.u >> 16);
}
__device__ __forceinline__ f32x16 zero16() {
  f32x16 v;
#pragma unroll
  for (int i = 0; i < 16; ++i) v[i] = 0.0f;
  return v;
}
// swizzled bf16 index: pitch 128, 16B groups XOR'd by row&15
__device__ __forceinline__ int xswz(int row, int g) {
  return row * 128 + ((g ^ (row & 15)) << 3);
}
// barrier draining LDS ops only — register-bound global loads stay in flight
__device__ __forceinline__ void barrier_lds() {
  asm volatile("s_waitcnt lgkmcnt(0)\n\ts_barrier" ::: "memory");
}

// ---------------------------------------------------------------------------
// Weight prep (layout unchanged): fragment f = kc*nbN + nb,
//   value = W[kc*16 + (lane>>5)*8 + j][nb*32 + (lane&31)]
// cl4 split into W1 = Wtop - 0.25*Wbot and W2 = 0.25*Wbot. dec padded N16->32.
// ---------------------------------------------------------------------------
__global__ void prep_weights(const float* __restrict__ enc_w, const float* __restrict__ fc1_w,
                             const float* __restrict__ fc2_w, const float* __restrict__ fc3_w,
                             const float* __restrict__ cl4_w, const float* __restrict__ dec_w,
                             unsigned short* __restrict__ ws) {
  int idx = blockIdx.x * 256 + threadIdx.x;
  if (idx >= WS_HALF) return;
  const float* W; int base, N, nbN, mode;
  if      (idx <  8192) { W = enc_w; base = SEG_ENC; N = 128; nbN = 4; mode = 0; }
  else if (idx < 24576) { W = fc1_w; base = SEG_FC1; N = 128; nbN = 4; mode = 0; }
  else if (idx < 40960) { W = fc2_w; base = SEG_FC2; N = 128; nbN = 4; mode = 0; }
  else if (idx < 57344) { W = fc3_w; base = SEG_FC3; N = 128; nbN = 4; mode = 0; }
  else if (idx < 73728) { W = cl4_w; base = SEG_W1;  N = 128; nbN = 4; mode = 1; }
  else if (idx < 90112) { W = cl4_w; base = SEG_W2;  N = 128; nbN = 4; mode = 2; }
  else                  { W = dec_w; base = SEG_DEC; N = 16;  nbN = 1; mode = 0; }
  int local = idx - base;
  int j    = local & 7;
  int lane = (local >> 3) & 63;
  int frag = local >> 9;
  int nb = frag % nbN;
  int kc = frag / nbN;
  int k = kc * 16 + ((lane >> 5) << 3) + j;
  int n = nb * 32 + (lane & 31);
  float wv;
  if (mode == 0)      wv = (n < N) ? W[k * N + n] : 0.0f;
  else if (mode == 1) wv = W[k * 128 + n] - 0.25f * W[(k + 128) * 128 + n];
  else                wv = 0.25f * W[(k + 128) * 128 + n];
  unsigned short hi = bf16_rn(wv);
  ws[idx]           = hi;
  ws[WS_HALF + idx] = bf16_rn(wv - bf16_f32(hi));
}

// ---------------------------------------------------------------------------
// Standard layer: X[64][K] @ W[K][128] + b, act, in-place into Xhi/Xlo.
// Operand-swapped: acc = W_frag (A-slot) x X_frag (B-slot) = (X@W)^T tile.
// Lane owns X/output row (acc0: lr, acc1: lr+32); reg-quad q = 4 consecutive
// output cols w*32 + 8q + 4lh + t -> vectorized ds_write_b64 epilogue.
// ---------------------------------------------------------------------------
template <int KC, int ACT>
__device__ __forceinline__ void layer_std(short* __restrict__ Xhi, short* __restrict__ Xlo,
                                          const unsigned short* __restrict__ whi,
                                          const unsigned short* __restrict__ wlo,
                                          const float* __restrict__ bias,
                                          int lr, int lh, int w) {
  const int l = lh * 32 + lr;
  f32x16 acc0 = zero16(), acc1 = zero16();
  const unsigned short* bh = whi + w * 512 + l * 8;
  const unsigned short* bl = wlo + w * 512 + l * 8;
  bf16x8 Bh[3], Bl[3];
  Bh[0] = *(const bf16x8*)(bh);
  Bl[0] = *(const bf16x8*)(bl);
  if (KC > 1) {
    Bh[1] = *(const bf16x8*)(bh + 2048);
    Bl[1] = *(const bf16x8*)(bl + 2048);
  }
  // bias prefetch: 16 values (4 quads), latency hidden under the K-loop
  f32x4 bv[4];
#pragma unroll
  for (int q = 0; q < 4; ++q)
    bv[q] = *(const f32x4*)&bias[w * 32 + q * 8 + 4 * lh];
  barrier_lds();   // X from previous phase visible (B/bias loads in flight)
#pragma unroll
  for (int kc = 0; kc < KC; ++kc) {
    const int cur = kc % 3;
    if (kc + 2 < KC) {
      const int nx = (kc + 2) % 3;
      Bh[nx] = *(const bf16x8*)(bh + (kc + 2) * 2048);
      Bl[nx] = *(const bf16x8*)(bl + (kc + 2) * 2048);
    }
    const int g = kc * 2 + lh;
    const int xi0 = xswz(lr, g), xi1 = xswz(lr + 32, g);
    const bf16x8 ah0 = *(const bf16x8*)&Xhi[xi0];
    const bf16x8 al0 = *(const bf16x8*)&Xlo[xi0];
    const bf16x8 ah1 = *(const bf16x8*)&Xhi[xi1];
    const bf16x8 al1 = *(const bf16x8*)&Xlo[xi1];
    acc0 = MFMA(Bh[cur], ah0, acc0);   // W_hi x X_hi
    acc1 = MFMA(Bh[cur], ah1, acc1);
    acc0 = MFMA(Bh[cur], al0, acc0);   // W_hi x X_lo
    acc1 = MFMA(Bh[cur], al1, acc1);
    acc0 = MFMA(Bl[cur], ah0, acc0);   // W_lo x X_hi
    acc1 = MFMA(Bl[cur], ah1, acc1);
  }
  barrier_lds();   // all waves done reading X -> in-place write safe
#pragma unroll
  for (int mb = 0; mb < 2; ++mb) {
    const int row = mb * 32 + lr;
    const int rb = row & 15;
    const f32x16 a = mb ? acc1 : acc0;
#pragma unroll
    for (int q = 0; q < 4; ++q) {
      bf16x4 hq, lq;
#pragma unroll
      for (int t = 0; t < 4; ++t) {
        float v = a[q * 4 + t] + bv[q][t];
        if (ACT == 0)      v = __builtin_amdgcn_rcpf(1.0f + __expf(-v));  // sigmoid
        else if (ACT == 1) v = fmaxf(v, 0.0f);                            // relu
        short h, lo2;
        split_hl(v, h, lo2);
        hq[t] = h; lq[t] = lo2;
      }
      const int idx = row * 128 + (((w * 4 + q) ^ rb) << 3) + 4 * lh;
      *(bf16x4*)&Xhi[idx] = hq;
      *(bf16x4*)&Xlo[idx] = lq;
    }
  }
}

// ---------------------------------------------------------------------------
// cl4 band MB (rows MB*32..+31, cols w*32..+31), operand-swapped:
// a1 = (H3@W1)^T, a2 = (H3@W2)^T. Lane owns row MB*32+lr; the 4 agents of
// one batch are ADJACENT LANES 4b..4b+3 -> T = shfl_xor(1)+shfl_xor(2).
// res = a1 + T + bias (per-reg cols).
// ---------------------------------------------------------------------------
template <int MB>
__device__ __forceinline__ f32x16 cl4_band(const short* __restrict__ Xhi,
                                           const short* __restrict__ Xlo,
                                           const unsigned short* __restrict__ whi,
                                           const unsigned short* __restrict__ wlo,
                                           const float* __restrict__ cl4_b,
                                           int lr, int lh, int w) {
  const int l = lh * 32 + lr;
  f32x16 a1 = zero16(), a2 = zero16();
  const unsigned short* b1h = whi + SEG_W1 + w * 512 + l * 8;
  const unsigned short* b1l = wlo + SEG_W1 + w * 512 + l * 8;
  const unsigned short* b2h = whi + SEG_W2 + w * 512 + l * 8;
  const unsigned short* b2l = wlo + SEG_W2 + w * 512 + l * 8;
  bf16x8 B1h[2], B1l[2], B2h[2], B2l[2];
  B1h[0] = *(const bf16x8*)(b1h);
  B1l[0] = *(const bf16x8*)(b1l);
  B2h[0] = *(const bf16x8*)(b2h);
  B2l[0] = *(const bf16x8*)(b2l);
  f32x4 bv[4];
#pragma unroll
  for (int q = 0; q < 4; ++q)
    bv[q] = *(const f32x4*)&cl4_b[w * 32 + q * 8 + 4 * lh];
#pragma unroll
  for (int kc = 0; kc < 8; ++kc) {
    const int cur = kc & 1;
    if (kc < 7) {
      const int nx = cur ^ 1;
      B1h[nx] = *(const bf16x8*)(b1h + (kc + 1) * 2048);
      B1l[nx] = *(const bf16x8*)(b1l + (kc + 1) * 2048);
      B2h[nx] = *(const bf16x8*)(b2h + (kc + 1) * 2048);
      B2l[nx] = *(const bf16x8*)(b2l + (kc + 1) * 2048);
    }
    const int xi = xswz(MB * 32 + lr, kc * 2 + lh);
    const bf16x8 ah = *(const bf16x8*)&Xhi[xi];
    const bf16x8 al = *(const bf16x8*)&Xlo[xi];
    a1 = MFMA(B1h[cur], ah, a1);
    a2 = MFMA(B2h[cur], ah, a2);
    a1 = MFMA(B1h[cur], al, a1);
    a2 = MFMA(B2h[cur], al, a2);
    a1 = MFMA(B1l[cur], ah, a1);
    a2 = MFMA(B2l[cur], ah, a2);
  }
  f32x16 res;
#pragma unroll
  for (int r = 0; r < 16; ++r) {
    float t2 = a2[r];
    t2 += __shfl_xor(t2, 1);   // agents are adjacent lanes 4b..4b+3
    t2 += __shfl_xor(t2, 2);
    res[r] = a1[r] + t2 + bv[r >> 2][r & 3];
  }
  return res;
}

// write one band's H4 result (lane = row MB*32+lr, reg-quads = col quads)
template <int MB>
__device__ __forceinline__ void cl4_write(short* __restrict__ Xhi, short* __restrict__ Xlo,
                                          const f32x16& rs, int lr, int lh, int w) {
  const int row = MB * 32 + lr;
  const int rb = row & 15;
#pragma unroll
  for (int q = 0; q < 4; ++q) {
    bf16x4 hq, lq;
#pragma unroll
    for (int t = 0; t < 4; ++t) {
      short h, lo2;
      split_hl(rs[q * 4 + t], h, lo2);
      hq[t] = h; lq[t] = lo2;
    }
    const int idx = row * 128 + (((w * 4 + q) ^ rb) << 3) + 4 * lh;
    *(bf16x4*)&Xhi[idx] = hq;
    *(bf16x4*)&Xlo[idx] = lq;
  }
}

// ---------------------------------------------------------------------------
__global__ __launch_bounds__(256, 3)
void commnet_fwd(const float* __restrict__ O,
                 const float* __restrict__ enc_b, const float* __restrict__ fc1_b,
                 const float* __restrict__ fc2_b, const float* __restrict__ fc3_b,
                 const float* __restrict__ cl4_b, const float* __restrict__ dec_b,
                 const unsigned short* __restrict__ ws, float* __restrict__ out) {
  __shared__ __attribute__((aligned(16))) short Xhi[64 * 128];  // 16 KB
  __shared__ __attribute__((aligned(16))) short Xlo[64 * 128];  // 16 KB
  __shared__ __attribute__((aligned(16))) float Pbuf[272];      // 1.06 KB (16x17)

  const int tid = threadIdx.x;
  const int l = tid & 63, w = tid >> 6;
  const int lr = l & 31, lh = l >> 5;

  // zero ALL 272 partial slots (R9 bug: tail 256..271 was left as stale LDS)
  Pbuf[tid] = 0.0f;
  if (tid < 16) Pbuf[256 + tid] = 0.0f;

  // ---- stage O [64 x 64] f32 -> split -> swizzled Xhi/Xlo groups 0..7 ----
  {
    const f32x4* Og = (const f32x4*)(O + (long)blockIdx.x * 4096);
#pragma unroll
    for (int it = 0; it < 4; ++it) {
      const int i = it * 256 + tid;       // 0..1023
      const int row = i >> 4;
      const int c4 = (i & 15) << 2;
      f32x4 v = Og[i];
      bf16x4 hv, lv;
#pragma unroll
      for (int j = 0; j < 4; ++j) {
        short hh, ll;
        split_hl(v[j], hh, ll);
        hv[j] = hh; lv[j] = ll;
      }
      const int bi = row * 128 + (((c4 >> 3) ^ (row & 15)) << 3) + (c4 & 7);
      *(bf16x4*)&Xhi[bi] = hv;
      *(bf16x4*)&Xlo[bi] = lv;
    }
  }

  const unsigned short* whi = ws;
  const unsigned short* wlo = ws + WS_HALF;

  layer_std<4, 0>(Xhi, Xlo, whi + SEG_ENC, wlo + SEG_ENC, enc_b, lr, lh, w);
  layer_std<8, 1>(Xhi, Xlo, whi + SEG_FC1, wlo + SEG_FC1, fc1_b, lr, lh, w);
  layer_std<8, 1>(Xhi, Xlo, whi + SEG_FC2, wlo + SEG_FC2, fc2_b, lr, lh, w);
  layer_std<8, 1>(Xhi, Xlo, whi + SEG_FC3, wlo + SEG_FC3, fc3_b, lr, lh, w);

  // ---- cl4: band0 -> flush -> band1 -> flush (acc peak = 32) ----
  barrier_lds();   // H3 (fc3 epilogue) visible
  {
    const f32x16 res0 = cl4_band<0>(Xhi, Xlo, whi, wlo, cl4_b, lr, lh, w);
    barrier_lds();  // all waves done reading rows 0-31
    cl4_write<0>(Xhi, Xlo, res0, lr, lh, w);   // rows 0-31, disjoint from band1 reads
  }
  {
    const f32x16 res1 = cl4_band<1>(Xhi, Xlo, whi, wlo, cl4_b, lr, lh, w);
    barrier_lds();  // all waves done reading rows 32-63
    cl4_write<1>(Xhi, Xlo, res1, lr, lh, w);
  }
  barrier_lds();   // H4 fully visible

  // ---- dec: [16 x 512] @ dec_w(pad32); 8 kc per wave; LDS atomic reduce ----
  {
    f32x16 dacc = zero16();
    const unsigned short* bh = whi + SEG_DEC + (w * 8) * 512 + l * 8;
    const unsigned short* bl = wlo + SEG_DEC + (w * 8) * 512 + l * 8;
    bf16x8 Bh[2], Bl[2];
    Bh[0] = *(const bf16x8*)(bh);
    Bl[0] = *(const bf16x8*)(bl);
#pragma unroll
    for (int kq = 0; kq < 8; ++kq) {
      const int cur = kq & 1;
      if (kq < 7) {
        Bh[cur ^ 1] = *(const bf16x8*)(bh + (kq + 1) * 512);
        Bl[cur ^ 1] = *(const bf16x8*)(bl + (kq + 1) * 512);
      }
      const int kcg = w * 8 + kq;          // global k-chunk 0..31
      const int k0 = kcg * 16 + lh * 8;    // 0..504
      const int agent = k0 >> 7;
      const int d0 = k0 & 127;
      const int row = (lr & 15) * 4 + agent;   // batch (dup for lr>=16), agent
      const int xi = xswz(row, d0 >> 3);
      const bf16x8 ah = *(const bf16x8*)&Xhi[xi];
      const bf16x8 al = *(const bf16x8*)&Xlo[xi];
      dacc = MFMA(Bh[cur], ah, dacc);      // swapped: weights in A-slot
      dacc = MFMA(Bh[cur], al, dacc);
      dacc = MFMA(Bl[cur], ah, dacc);
    }
    if (lr < 16) {   // lane = batch; reg r -> action (r&3)+8*(r>>2)+4*lh
#pragma unroll
      for (int r = 0; r < 8; ++r) {
        const int action = (r & 3) + 8 * (r >> 2) + 4 * lh;   // 0..15
        atomicAdd(&Pbuf[lr * 17 + action], dacc[r]);
      }
    }
  }
  barrier_lds();   // partials complete

  // ---- + bias, softmax over 16 actions, coalesced store ----
  {
    const int c = tid & 15;
    float v = Pbuf[(tid >> 4) * 17 + c] + dec_b[c];
    float m = v;
#pragma unroll
    for (int mk = 1; mk < 16; mk <<= 1) m = fmaxf(m, __shfl_xor(m, mk, 16));
    const float e = __expf(v - m);
    float s = e;
#pragma unroll
    for (int mk = 1; mk < 16; mk <<= 1) s += __shfl_xor(s, mk, 16);
    out[(long)blockIdx.x * 256 + tid] = e * __builtin_amdgcn_rcpf(s);
  }
}

// ---------------------------------------------------------------------------
extern "C" void kernel_launch(void* const* d_in, const int* in_sizes, int n_in,
                              void* d_out, int out_size, void* d_ws, size_t ws_size,
                              hipStream_t stream) {
  (void)n_in; (void)out_size; (void)ws_size;  // needs ws_size >= 425,984 B
  const float* O     = (const float*)d_in[0];
  const float* enc_w = (const float*)d_in[1];
  const float* enc_b = (const float*)d_in[2];
  const float* fc1_w = (const float*)d_in[3];
  const float* fc1_b = (const float*)d_in[4];
  const float* fc2_w = (const float*)d_in[5];
  const float* fc2_b = (const float*)d_in[6];
  const float* fc3_w = (const float*)d_in[7];
  const float* fc3_b = (const float*)d_in[8];
  const float* cl4_w = (const float*)d_in[9];
  const float* cl4_b = (const float*)d_in[10];
  const float* dec_w = (const float*)d_in[11];
  const float* dec_b = (const float*)d_in[12];
  unsigned short* wsb = (unsigned short*)d_ws;

  prep_weights<<<(WS_HALF + 255) / 256, 256, 0, stream>>>(enc_w, fc1_w, fc2_w, fc3_w,
                                                          cl4_w, dec_w, wsb);
  const int rows   = in_sizes[0] / 64;   // B*A = 262144
  const int blocks = rows / 64;          // 4096
  commnet_fwd<<<blocks, 256, 0, stream>>>(O, enc_b, fc1_b, fc2_b, fc3_b, cl4_b,
                                          dec_b, wsb, (float*)d_out);
}

// Round 11
// 97.093 us; speedup vs baseline: 1.8866x; 1.8721x over previous
//
#include <hip/hip_runtime.h>
#include <stdint.h>

// ---------------------------------------------------------------------------
// CommNetActor fused forward v11 — PURE FP16 MFMA (gfx950).
//
//  R10 post-mortem: v7/v8/v10 all plateau at 185-193us with MFMA 70us busy,
//  VALU 60us, LDS 50us — latency/barrier bound, every pipe 3x inflated by
//  bf16x3. The observed absmax 4.88e-4 is bit-identical across all passing
//  rounds -> it's the comparison quantization floor, not our arithmetic.
//  v11 pivots precision: fp16 RN error 2^-12 is 8x better than bf16 ->
//  single-product MFMA (mfma_f32_32x32x16_f16) should land ~1.5e-4 of
//  arithmetic error, under the 1.33e-3 threshold with margin.
//   - 3x fewer MFMA (96/wave vs 288), 2x less LDS traffic + epilogue VALU
//     (single X array, no hi/lo split), weight stream halves (212KB ws).
//   - Same fragment layout/swizzle (2B elements unchanged).
//   - Config: (256,4), 17.3KB LDS, distinct 32-col wave ownership, fused
//     comm-in-lane cl4 (shfl_xor over adjacent agent lanes), atomic dec.
//  MFMA C/D: col=lane&31, row=(r&3)+8*(r>>2)+4*(lane>>5)  [HW-verified].
// ---------------------------------------------------------------------------

typedef __attribute__((ext_vector_type(4)))  float f32x4;
typedef __attribute__((ext_vector_type(16))) float f32x16;
typedef __attribute__((ext_vector_type(8)))  _Float16 f16x8;
typedef __attribute__((ext_vector_type(4)))  _Float16 f16x4;

#define WS_HALF 106496   // total f16 elements in ws (single precision level now)
#define SEG_ENC 0
#define SEG_FC1 8192
#define SEG_FC2 24576
#define SEG_FC3 40960
#define SEG_W1  57344
#define SEG_W2  73728
#define SEG_DEC 90112

#define MFMA16(a, b, c) __builtin_amdgcn_mfma_f32_32x32x16_f16((a), (b), (c), 0, 0, 0)

__device__ __forceinline__ unsigned short f16_bits(float f) {
  union { _Float16 h; unsigned short u; } cv;
  cv.h = (_Float16)f;   // RN-E
  return cv.u;
}
__device__ __forceinline__ f32x16 zero16() {
  f32x16 v;
#pragma unroll
  for (int i = 0; i < 16; ++i) v[i] = 0.0f;
  return v;
}
// swizzled f16 index: pitch 128, 16B groups XOR'd by row&15
__device__ __forceinline__ int xswz(int row, int g) {
  return row * 128 + ((g ^ (row & 15)) << 3);
}
// barrier draining LDS ops only — register-bound global loads stay in flight
__device__ __forceinline__ void barrier_lds() {
  asm volatile("s_waitcnt lgkmcnt(0)\n\ts_barrier" ::: "memory");
}

// ---------------------------------------------------------------------------
// Weight prep: f16 fragments. Frag f = kc*nbN + nb:
//   value = W[kc*16 + (lane>>5)*8 + j][nb*32 + (lane&31)]
// cl4 split into W1 = Wtop - 0.25*Wbot and W2 = 0.25*Wbot. dec padded N16->32.
// ---------------------------------------------------------------------------
__global__ void prep_weights(const float* __restrict__ enc_w, const float* __restrict__ fc1_w,
                             const float* __restrict__ fc2_w, const float* __restrict__ fc3_w,
                             const float* __restrict__ cl4_w, const float* __restrict__ dec_w,
                             unsigned short* __restrict__ ws) {
  int idx = blockIdx.x * 256 + threadIdx.x;
  if (idx >= WS_HALF) return;
  const float* W; int base, N, nbN, mode;
  if      (idx <  8192) { W = enc_w; base = SEG_ENC; N = 128; nbN = 4; mode = 0; }
  else if (idx < 24576) { W = fc1_w; base = SEG_FC1; N = 128; nbN = 4; mode = 0; }
  else if (idx < 40960) { W = fc2_w; base = SEG_FC2; N = 128; nbN = 4; mode = 0; }
  else if (idx < 57344) { W = fc3_w; base = SEG_FC3; N = 128; nbN = 4; mode = 0; }
  else if (idx < 73728) { W = cl4_w; base = SEG_W1;  N = 128; nbN = 4; mode = 1; }
  else if (idx < 90112) { W = cl4_w; base = SEG_W2;  N = 128; nbN = 4; mode = 2; }
  else                  { W = dec_w; base = SEG_DEC; N = 16;  nbN = 1; mode = 0; }
  int local = idx - base;
  int j    = local & 7;
  int lane = (local >> 3) & 63;
  int frag = local >> 9;
  int nb = frag % nbN;
  int kc = frag / nbN;
  int k = kc * 16 + ((lane >> 5) << 3) + j;
  int n = nb * 32 + (lane & 31);
  float wv;
  if (mode == 0)      wv = (n < N) ? W[k * N + n] : 0.0f;
  else if (mode == 1) wv = W[k * 128 + n] - 0.25f * W[(k + 128) * 128 + n];
  else                wv = 0.25f * W[(k + 128) * 128 + n];
  ws[idx] = f16_bits(wv);
}

// ---------------------------------------------------------------------------
// Standard layer: X[64][K] @ W[K][128] + b, act, in-place into Xh (f16).
// Operand-swapped: acc = W_frag (A-slot) x X_frag (B-slot) = (X@W)^T tile.
// Lane owns output row (acc0: lr, acc1: lr+32); reg-quad q = 4 consecutive
// output cols w*32 + 8q + 4lh + t -> 8B ds_write epilogue.
// ---------------------------------------------------------------------------
template <int KC, int ACT>
__device__ __forceinline__ void layer_std(short* __restrict__ Xh,
                                          const unsigned short* __restrict__ wseg,
                                          const float* __restrict__ bias,
                                          int lr, int lh, int w) {
  const int l = lh * 32 + lr;
  f32x16 acc0 = zero16(), acc1 = zero16();
  const unsigned short* bp = wseg + w * 512 + l * 8;
  f16x8 Bh[3];
  Bh[0] = *(const f16x8*)(bp);
  if (KC > 1) Bh[1] = *(const f16x8*)(bp + 2048);
  // bias prefetch: 16 values (4 quads), latency hidden under the K-loop
  f32x4 bv[4];
#pragma unroll
  for (int q = 0; q < 4; ++q)
    bv[q] = *(const f32x4*)&bias[w * 32 + q * 8 + 4 * lh];
  barrier_lds();   // X from previous phase visible (B/bias loads in flight)
#pragma unroll
  for (int kc = 0; kc < KC; ++kc) {
    const int cur = kc % 3;
    if (kc + 2 < KC) {
      Bh[(kc + 2) % 3] = *(const f16x8*)(bp + (kc + 2) * 2048);
    }
    const int g = kc * 2 + lh;
    const int xi0 = xswz(lr, g), xi1 = xswz(lr + 32, g);
    const f16x8 ah0 = *(const f16x8*)&Xh[xi0];
    const f16x8 ah1 = *(const f16x8*)&Xh[xi1];
    acc0 = MFMA16(Bh[cur], ah0, acc0);
    acc1 = MFMA16(Bh[cur], ah1, acc1);
  }
  barrier_lds();   // all waves done reading X -> in-place write safe
#pragma unroll
  for (int mb = 0; mb < 2; ++mb) {
    const int row = mb * 32 + lr;
    const int rb = row & 15;
    const f32x16 a = mb ? acc1 : acc0;
#pragma unroll
    for (int q = 0; q < 4; ++q) {
      f16x4 hq;
#pragma unroll
      for (int t = 0; t < 4; ++t) {
        float v = a[q * 4 + t] + bv[q][t];
        if (ACT == 0)      v = __builtin_amdgcn_rcpf(1.0f + __expf(-v));  // sigmoid
        else if (ACT == 1) v = fmaxf(v, 0.0f);                            // relu
        hq[t] = (_Float16)v;
      }
      const int idx = row * 128 + (((w * 4 + q) ^ rb) << 3) + 4 * lh;
      *(f16x4*)&Xh[idx] = hq;
    }
  }
}

// ---------------------------------------------------------------------------
// cl4 band MB (rows MB*32..+31, cols w*32..+31), operand-swapped:
// a1 = (H3@W1)^T, a2 = (H3@W2)^T. Lane owns row MB*32+lr; the 4 agents of
// one batch are ADJACENT LANES 4b..4b+3 -> T = shfl_xor(1)+shfl_xor(2).
// res = a1 + T + bias (per-reg cols).
// ---------------------------------------------------------------------------
template <int MB>
__device__ __forceinline__ f32x16 cl4_band(const short* __restrict__ Xh,
                                           const unsigned short* __restrict__ ws,
                                           const float* __restrict__ cl4_b,
                                           int lr, int lh, int w) {
  const int l = lh * 32 + lr;
  f32x16 a1 = zero16(), a2 = zero16();
  const unsigned short* b1p = ws + SEG_W1 + w * 512 + l * 8;
  const unsigned short* b2p = ws + SEG_W2 + w * 512 + l * 8;
  f16x8 B1[2], B2[2];
  B1[0] = *(const f16x8*)(b1p);
  B2[0] = *(const f16x8*)(b2p);
  f32x4 bv[4];
#pragma unroll
  for (int q = 0; q < 4; ++q)
    bv[q] = *(const f32x4*)&cl4_b[w * 32 + q * 8 + 4 * lh];
#pragma unroll
  for (int kc = 0; kc < 8; ++kc) {
    const int cur = kc & 1;
    if (kc < 7) {
      const int nx = cur ^ 1;
      B1[nx] = *(const f16x8*)(b1p + (kc + 1) * 2048);
      B2[nx] = *(const f16x8*)(b2p + (kc + 1) * 2048);
    }
    const int xi = xswz(MB * 32 + lr, kc * 2 + lh);
    const f16x8 ah = *(const f16x8*)&Xh[xi];
    a1 = MFMA16(B1[cur], ah, a1);
    a2 = MFMA16(B2[cur], ah, a2);
  }
  f32x16 res;
#pragma unroll
  for (int r = 0; r < 16; ++r) {
    float t2 = a2[r];
    t2 += __shfl_xor(t2, 1);   // agents are adjacent lanes 4b..4b+3
    t2 += __shfl_xor(t2, 2);
    res[r] = a1[r] + t2 + bv[r >> 2][r & 3];
  }
  return res;
}

// write one band's H4 result (lane = row MB*32+lr, reg-quads = col quads)
template <int MB>
__device__ __forceinline__ void cl4_write(short* __restrict__ Xh,
                                          const f32x16& rs, int lr, int lh, int w) {
  const int row = MB * 32 + lr;
  const int rb = row & 15;
#pragma unroll
  for (int q = 0; q < 4; ++q) {
    f16x4 hq;
#pragma unroll
    for (int t = 0; t < 4; ++t) hq[t] = (_Float16)rs[q * 4 + t];
    const int idx = row * 128 + (((w * 4 + q) ^ rb) << 3) + 4 * lh;
    *(f16x4*)&Xh[idx] = hq;
  }
}

// ---------------------------------------------------------------------------
__global__ __launch_bounds__(256, 4)
void commnet_fwd(const float* __restrict__ O,
                 const float* __restrict__ enc_b, const float* __restrict__ fc1_b,
                 const float* __restrict__ fc2_b, const float* __restrict__ fc3_b,
                 const float* __restrict__ cl4_b, const float* __restrict__ dec_b,
                 const unsigned short* __restrict__ ws, float* __restrict__ out) {
  __shared__ __attribute__((aligned(16))) short Xh[64 * 128];   // 16 KB
  __shared__ __attribute__((aligned(16))) float Pbuf[272];      // 1.06 KB (16x17)

  const int tid = threadIdx.x;
  const int l = tid & 63, w = tid >> 6;
  const int lr = l & 31, lh = l >> 5;

  // zero ALL 272 partial slots (R9 lesson: stale LDS in the tail)
  Pbuf[tid] = 0.0f;
  if (tid < 16) Pbuf[256 + tid] = 0.0f;

  // ---- stage O [64 x 64] f32 -> f16 -> swizzled Xh groups 0..7 ----
  {
    const f32x4* Og = (const f32x4*)(O + (long)blockIdx.x * 4096);
#pragma unroll
    for (int it = 0; it < 4; ++it) {
      const int i = it * 256 + tid;       // 0..1023
      const int row = i >> 4;
      const int c4 = (i & 15) << 2;
      f32x4 v = Og[i];
      f16x4 hv;
#pragma unroll
      for (int j = 0; j < 4; ++j) hv[j] = (_Float16)v[j];
      const int bi = row * 128 + (((c4 >> 3) ^ (row & 15)) << 3) + (c4 & 7);
      *(f16x4*)&Xh[bi] = hv;
    }
  }

  layer_std<4, 0>(Xh, ws + SEG_ENC, enc_b, lr, lh, w);
  layer_std<8, 1>(Xh, ws + SEG_FC1, fc1_b, lr, lh, w);
  layer_std<8, 1>(Xh, ws + SEG_FC2, fc2_b, lr, lh, w);
  layer_std<8, 1>(Xh, ws + SEG_FC3, fc3_b, lr, lh, w);

  // ---- cl4: band0 -> flush -> band1 -> flush (acc peak = 32) ----
  barrier_lds();   // H3 (fc3 epilogue) visible
  {
    const f32x16 res0 = cl4_band<0>(Xh, ws, cl4_b, lr, lh, w);
    barrier_lds();  // all waves done reading rows 0-31
    cl4_write<0>(Xh, res0, lr, lh, w);   // rows 0-31, disjoint from band1 reads
  }
  {
    const f32x16 res1 = cl4_band<1>(Xh, ws, cl4_b, lr, lh, w);
    barrier_lds();  // all waves done reading rows 32-63
    cl4_write<1>(Xh, res1, lr, lh, w);
  }
  barrier_lds();   // H4 fully visible

  // ---- dec: [16 x 512] @ dec_w(pad32); 8 kc per wave; LDS atomic reduce ----
  {
    f32x16 dacc = zero16();
    const unsigned short* bp = ws + SEG_DEC + (w * 8) * 512 + l * 8;
    f16x8 Bh[2];
    Bh[0] = *(const f16x8*)(bp);
#pragma unroll
    for (int kq = 0; kq < 8; ++kq) {
      const int cur = kq & 1;
      if (kq < 7) {
        Bh[cur ^ 1] = *(const f16x8*)(bp + (kq + 1) * 512);
      }
      const int kcg = w * 8 + kq;          // global k-chunk 0..31
      const int k0 = kcg * 16 + lh * 8;    // 0..504
      const int agent = k0 >> 7;
      const int d0 = k0 & 127;
      const int row = (lr & 15) * 4 + agent;   // batch (dup for lr>=16), agent
      const int xi = xswz(row, d0 >> 3);
      const f16x8 ah = *(const f16x8*)&Xh[xi];
      dacc = MFMA16(Bh[cur], ah, dacc);    // swapped: weights in A-slot
    }
    if (lr < 16) {   // lane = batch; reg r -> action (r&3)+8*(r>>2)+4*lh
#pragma unroll
      for (int r = 0; r < 8; ++r) {
        const int action = (r & 3) + 8 * (r >> 2) + 4 * lh;   // 0..15
        atomicAdd(&Pbuf[lr * 17 + action], dacc[r]);
      }
    }
  }
  barrier_lds();   // partials complete

  // ---- + bias, softmax over 16 actions, coalesced store ----
  {
    const int c = tid & 15;
    float v = Pbuf[(tid >> 4) * 17 + c] + dec_b[c];
    float m = v;
#pragma unroll
    for (int mk = 1; mk < 16; mk <<= 1) m = fmaxf(m, __shfl_xor(m, mk, 16));
    const float e = __expf(v - m);
    float s = e;
#pragma unroll
    for (int mk = 1; mk < 16; mk <<= 1) s += __shfl_xor(s, mk, 16);
    out[(long)blockIdx.x * 256 + tid] = e * __builtin_amdgcn_rcpf(s);
  }
}

// ---------------------------------------------------------------------------
extern "C" void kernel_launch(void* const* d_in, const int* in_sizes, int n_in,
                              void* d_out, int out_size, void* d_ws, size_t ws_size,
                              hipStream_t stream) {
  (void)n_in; (void)out_size; (void)ws_size;  // needs ws_size >= 212,992 B
  const float* O     = (const float*)d_in[0];
  const float* enc_w = (const float*)d_in[1];
  const float* enc_b = (const float*)d_in[2];
  const float* fc1_w = (const float*)d_in[3];
  const float* fc1_b = (const float*)d_in[4];
  const float* fc2_w = (const float*)d_in[5];
  const float* fc2_b = (const float*)d_in[6];
  const float* fc3_w = (const float*)d_in[7];
  const float* fc3_b = (const float*)d_in[8];
  const float* cl4_w = (const float*)d_in[9];
  const float* cl4_b = (const float*)d_in[10];
  const float* dec_w = (const float*)d_in[11];
  const float* dec_b = (const float*)d_in[12];
  unsigned short* wsb = (unsigned short*)d_ws;

  prep_weights<<<(WS_HALF + 255) / 256, 256, 0, stream>>>(enc_w, fc1_w, fc2_w, fc3_w,
                                                          cl4_w, dec_w, wsb);
  const int rows   = in_sizes[0] / 64;   // B*A = 262144
  const int blocks = rows / 64;          // 4096
  commnet_fwd<<<blocks, 256, 0, stream>>>(O, enc_b, fc1_b, fc2_b, fc3_b, cl4_b,
                                          dec_b, wsb, (float*)d_out);
}

// Round 12
// 89.348 us; speedup vs baseline: 2.0502x; 1.0867x over previous
//
#include <hip/hip_runtime.h>
#include <stdint.h>

// ---------------------------------------------------------------------------
// CommNetActor fused forward v12 — FP16 MFMA, latency-tuned (gfx950).
//
//  R11 post-mortem: fp16 pivot 190->106us rocprof; absmax bit-identical
//  4.88e-4 (comparison floor). Now purely latency-bound: MFMA 21us busy,
//  VALU 23us, wall 106 — no pipe >23%. The stalls: (a) B-fragments stream
//  from L2 (~200cyc) with only 2-3 iterations of lookahead -> ~100cyc vmcnt
//  stall per K-iteration at ~3 waves/SIMD; (b) ~11 full-drain barriers.
//
//  v12, same arithmetic (absmax must stay bit-identical):
//   1. FULL-LAYER B preload into registers: std layers all KC chunks
//      (<=32 VGPR), cl4 ring-4 per matrix, dec all 8. K-loop has ZERO VMEM.
//   2. PING-PONG X (X0<->X1): layer reads Xsrc writes Xdst -> WAR barrier
//      gone; 1 barrier/layer (~7 total), none between cl4 bands.
//      LDS 33.9KB -> 4 blocks/CU.
//  Config: (256,4), distinct 32-col wave ownership, operand-swapped MFMA
//  (lane = output row, reg-quads = col quads), fused comm via shfl_xor,
//  atomic dec reduce. MFMA C/D: col=lane&31, row=(r&3)+8*(r>>2)+4*(lane>>5).
// ---------------------------------------------------------------------------

typedef __attribute__((ext_vector_type(4)))  float f32x4;
typedef __attribute__((ext_vector_type(16))) float f32x16;
typedef __attribute__((ext_vector_type(8)))  _Float16 f16x8;
typedef __attribute__((ext_vector_type(4)))  _Float16 f16x4;

#define WS_HALF 106496   // total f16 elements in ws
#define SEG_ENC 0
#define SEG_FC1 8192
#define SEG_FC2 24576
#define SEG_FC3 40960
#define SEG_W1  57344
#define SEG_W2  73728
#define SEG_DEC 90112

#define MFMA16(a, b, c) __builtin_amdgcn_mfma_f32_32x32x16_f16((a), (b), (c), 0, 0, 0)

__device__ __forceinline__ unsigned short f16_bits(float f) {
  union { _Float16 h; unsigned short u; } cv;
  cv.h = (_Float16)f;   // RN-E
  return cv.u;
}
__device__ __forceinline__ f32x16 zero16() {
  f32x16 v;
#pragma unroll
  for (int i = 0; i < 16; ++i) v[i] = 0.0f;
  return v;
}
// swizzled f16 index: pitch 128, 16B groups XOR'd by row&15
__device__ __forceinline__ int xswz(int row, int g) {
  return row * 128 + ((g ^ (row & 15)) << 3);
}
// barrier draining LDS ops only — register-bound global loads stay in flight
__device__ __forceinline__ void barrier_lds() {
  asm volatile("s_waitcnt lgkmcnt(0)\n\ts_barrier" ::: "memory");
}

// ---------------------------------------------------------------------------
// Weight prep: f16 fragments. Frag f = kc*nbN + nb:
//   value = W[kc*16 + (lane>>5)*8 + j][nb*32 + (lane&31)]
// cl4 split into W1 = Wtop - 0.25*Wbot and W2 = 0.25*Wbot. dec padded N16->32.
// ---------------------------------------------------------------------------
__global__ void prep_weights(const float* __restrict__ enc_w, const float* __restrict__ fc1_w,
                             const float* __restrict__ fc2_w, const float* __restrict__ fc3_w,
                             const float* __restrict__ cl4_w, const float* __restrict__ dec_w,
                             unsigned short* __restrict__ ws) {
  int idx = blockIdx.x * 256 + threadIdx.x;
  if (idx >= WS_HALF) return;
  const float* W; int base, N, nbN, mode;
  if      (idx <  8192) { W = enc_w; base = SEG_ENC; N = 128; nbN = 4; mode = 0; }
  else if (idx < 24576) { W = fc1_w; base = SEG_FC1; N = 128; nbN = 4; mode = 0; }
  else if (idx < 40960) { W = fc2_w; base = SEG_FC2; N = 128; nbN = 4; mode = 0; }
  else if (idx < 57344) { W = fc3_w; base = SEG_FC3; N = 128; nbN = 4; mode = 0; }
  else if (idx < 73728) { W = cl4_w; base = SEG_W1;  N = 128; nbN = 4; mode = 1; }
  else if (idx < 90112) { W = cl4_w; base = SEG_W2;  N = 128; nbN = 4; mode = 2; }
  else                  { W = dec_w; base = SEG_DEC; N = 16;  nbN = 1; mode = 0; }
  int local = idx - base;
  int j    = local & 7;
  int lane = (local >> 3) & 63;
  int frag = local >> 9;
  int nb = frag % nbN;
  int kc = frag / nbN;
  int k = kc * 16 + ((lane >> 5) << 3) + j;
  int n = nb * 32 + (lane & 31);
  float wv;
  if (mode == 0)      wv = (n < N) ? W[k * N + n] : 0.0f;
  else if (mode == 1) wv = W[k * 128 + n] - 0.25f * W[(k + 128) * 128 + n];
  else                wv = 0.25f * W[(k + 128) * 128 + n];
  ws[idx] = f16_bits(wv);
}

// ---------------------------------------------------------------------------
// Standard layer: Xsrc[64][K] @ W[K][128] + b, act -> Xdst (ping-pong, no
// internal barrier). Operand-swapped. ALL KC B-chunks preloaded to registers
// before the K-loop: zero VMEM inside the loop.
// ---------------------------------------------------------------------------
template <int KC, int ACT>
__device__ __forceinline__ void layer_std(const short* __restrict__ Xsrc,
                                          short* __restrict__ Xdst,
                                          const unsigned short* __restrict__ wseg,
                                          const float* __restrict__ bias,
                                          int lr, int lh, int w) {
  const int l = lh * 32 + lr;
  const unsigned short* bp = wseg + w * 512 + l * 8;
  f16x8 Bh[KC];
#pragma unroll
  for (int kc = 0; kc < KC; ++kc) Bh[kc] = *(const f16x8*)(bp + kc * 2048);
  f32x4 bv[4];
#pragma unroll
  for (int q = 0; q < 4; ++q)
    bv[q] = *(const f32x4*)&bias[w * 32 + q * 8 + 4 * lh];
  f32x16 acc0 = zero16(), acc1 = zero16();
#pragma unroll
  for (int kc = 0; kc < KC; ++kc) {
    const int g = kc * 2 + lh;
    const int xi0 = xswz(lr, g), xi1 = xswz(lr + 32, g);
    const f16x8 ah0 = *(const f16x8*)&Xsrc[xi0];
    const f16x8 ah1 = *(const f16x8*)&Xsrc[xi1];
    acc0 = MFMA16(Bh[kc], ah0, acc0);
    acc1 = MFMA16(Bh[kc], ah1, acc1);
  }
#pragma unroll
  for (int mb = 0; mb < 2; ++mb) {
    const int row = mb * 32 + lr;
    const int rb = row & 15;
    const f32x16 a = mb ? acc1 : acc0;
#pragma unroll
    for (int q = 0; q < 4; ++q) {
      f16x4 hq;
#pragma unroll
      for (int t = 0; t < 4; ++t) {
        float v = a[q * 4 + t] + bv[q][t];
        if (ACT == 0)      v = __builtin_amdgcn_rcpf(1.0f + __expf(-v));  // sigmoid
        else if (ACT == 1) v = fmaxf(v, 0.0f);                            // relu
        hq[t] = (_Float16)v;
      }
      const int idx = row * 128 + (((w * 4 + q) ^ rb) << 3) + 4 * lh;
      *(f16x4*)&Xdst[idx] = hq;
    }
  }
}

// ---------------------------------------------------------------------------
// cl4 band MB (rows MB*32..+31, cols w*32..+31): a1=(H3@W1)^T, a2=(H3@W2)^T,
// ring-4 B prefetch per matrix (8 chunks in flight). Agents = adjacent lanes
// -> T = shfl_xor(1)+shfl_xor(2). Writes H4 to Xdst (ping-pong, no barrier).
// ---------------------------------------------------------------------------
template <int MB>
__device__ __forceinline__ void cl4_band(const short* __restrict__ Xsrc,
                                         short* __restrict__ Xdst,
                                         const unsigned short* __restrict__ ws,
                                         const float* __restrict__ cl4_b,
                                         int lr, int lh, int w) {
  const int l = lh * 32 + lr;
  const unsigned short* b1p = ws + SEG_W1 + w * 512 + l * 8;
  const unsigned short* b2p = ws + SEG_W2 + w * 512 + l * 8;
  f16x8 B1[4], B2[4];
#pragma unroll
  for (int k = 0; k < 4; ++k) {
    B1[k] = *(const f16x8*)(b1p + k * 2048);
    B2[k] = *(const f16x8*)(b2p + k * 2048);
  }
  f32x4 bv[4];
#pragma unroll
  for (int q = 0; q < 4; ++q)
    bv[q] = *(const f32x4*)&cl4_b[w * 32 + q * 8 + 4 * lh];
  f32x16 a1 = zero16(), a2 = zero16();
#pragma unroll
  for (int kc = 0; kc < 8; ++kc) {
    const int cur = kc & 3;
    const int xi = xswz(MB * 32 + lr, kc * 2 + lh);
    const f16x8 ah = *(const f16x8*)&Xsrc[xi];
    a1 = MFMA16(B1[cur], ah, a1);
    a2 = MFMA16(B2[cur], ah, a2);
    if (kc + 4 < 8) {
      B1[cur] = *(const f16x8*)(b1p + (kc + 4) * 2048);
      B2[cur] = *(const f16x8*)(b2p + (kc + 4) * 2048);
    }
  }
  const int row = MB * 32 + lr;
  const int rb = row & 15;
#pragma unroll
  for (int q = 0; q < 4; ++q) {
    f16x4 hq;
#pragma unroll
    for (int t = 0; t < 4; ++t) {
      const int r = q * 4 + t;
      float t2 = a2[r];
      t2 += __shfl_xor(t2, 1);   // agents are adjacent lanes 4b..4b+3
      t2 += __shfl_xor(t2, 2);
      hq[t] = (_Float16)(a1[r] + t2 + bv[q][t]);
    }
    const int idx = row * 128 + (((w * 4 + q) ^ rb) << 3) + 4 * lh;
    *(f16x4*)&Xdst[idx] = hq;
  }
}

// ---------------------------------------------------------------------------
__global__ __launch_bounds__(256, 4)
void commnet_fwd(const float* __restrict__ O,
                 const float* __restrict__ enc_b, const float* __restrict__ fc1_b,
                 const float* __restrict__ fc2_b, const float* __restrict__ fc3_b,
                 const float* __restrict__ cl4_b, const float* __restrict__ dec_b,
                 const unsigned short* __restrict__ ws, float* __restrict__ out) {
  __shared__ __attribute__((aligned(16))) short X0[64 * 128];   // 16 KB
  __shared__ __attribute__((aligned(16))) short X1[64 * 128];   // 16 KB
  __shared__ __attribute__((aligned(16))) float Pbuf[272];      // 1.06 KB (16x17)

  const int tid = threadIdx.x;
  const int l = tid & 63, w = tid >> 6;
  const int lr = l & 31, lh = l >> 5;

  // zero ALL 272 partial slots (R9 lesson: stale LDS in the tail)
  Pbuf[tid] = 0.0f;
  if (tid < 16) Pbuf[256 + tid] = 0.0f;

  // ---- stage O [64 x 64] f32 -> f16 -> swizzled X0 groups 0..7 ----
  {
    const f32x4* Og = (const f32x4*)(O + (long)blockIdx.x * 4096);
#pragma unroll
    for (int it = 0; it < 4; ++it) {
      const int i = it * 256 + tid;       // 0..1023
      const int row = i >> 4;
      const int c4 = (i & 15) << 2;
      f32x4 v = Og[i];
      f16x4 hv;
#pragma unroll
      for (int j = 0; j < 4; ++j) hv[j] = (_Float16)v[j];
      const int bi = row * 128 + (((c4 >> 3) ^ (row & 15)) << 3) + (c4 & 7);
      *(f16x4*)&X0[bi] = hv;
    }
  }
  barrier_lds();   // X0 staged

  layer_std<4, 0>(X0, X1, ws + SEG_ENC, enc_b, lr, lh, w);
  barrier_lds();   // H0 in X1
  layer_std<8, 1>(X1, X0, ws + SEG_FC1, fc1_b, lr, lh, w);
  barrier_lds();   // H1 in X0
  layer_std<8, 1>(X0, X1, ws + SEG_FC2, fc2_b, lr, lh, w);
  barrier_lds();   // H2 in X1
  layer_std<8, 1>(X1, X0, ws + SEG_FC3, fc3_b, lr, lh, w);
  barrier_lds();   // H3 in X0

  // ---- cl4: both bands read X0, write X1; no barrier between bands ----
  cl4_band<0>(X0, X1, ws, cl4_b, lr, lh, w);
  cl4_band<1>(X0, X1, ws, cl4_b, lr, lh, w);
  barrier_lds();   // H4 in X1

  // ---- dec: [16 x 512] @ dec_w(pad32); 8 kc/wave, ALL preloaded; atomics ----
  {
    const unsigned short* bp = ws + SEG_DEC + (w * 8) * 512 + l * 8;
    f16x8 Bh[8];
#pragma unroll
    for (int kq = 0; kq < 8; ++kq) Bh[kq] = *(const f16x8*)(bp + kq * 512);
    f32x16 dacc = zero16();
#pragma unroll
    for (int kq = 0; kq < 8; ++kq) {
      const int kcg = w * 8 + kq;          // global k-chunk 0..31
      const int k0 = kcg * 16 + lh * 8;    // 0..504
      const int agent = k0 >> 7;
      const int d0 = k0 & 127;
      const int row = (lr & 15) * 4 + agent;   // batch (dup for lr>=16), agent
      const int xi = xswz(row, d0 >> 3);
      const f16x8 ah = *(const f16x8*)&X1[xi];
      dacc = MFMA16(Bh[kq], ah, dacc);     // swapped: weights in A-slot
    }
    if (lr < 16) {   // lane = batch; reg r -> action (r&3)+8*(r>>2)+4*lh
#pragma unroll
      for (int r = 0; r < 8; ++r) {
        const int action = (r & 3) + 8 * (r >> 2) + 4 * lh;   // 0..15
        atomicAdd(&Pbuf[lr * 17 + action], dacc[r]);
      }
    }
  }
  barrier_lds();   // partials complete

  // ---- + bias, softmax over 16 actions, coalesced store ----
  {
    const int c = tid & 15;
    float v = Pbuf[(tid >> 4) * 17 + c] + dec_b[c];
    float m = v;
#pragma unroll
    for (int mk = 1; mk < 16; mk <<= 1) m = fmaxf(m, __shfl_xor(m, mk, 16));
    const float e = __expf(v - m);
    float s = e;
#pragma unroll
    for (int mk = 1; mk < 16; mk <<= 1) s += __shfl_xor(s, mk, 16);
    out[(long)blockIdx.x * 256 + tid] = e * __builtin_amdgcn_rcpf(s);
  }
}

// ---------------------------------------------------------------------------
extern "C" void kernel_launch(void* const* d_in, const int* in_sizes, int n_in,
                              void* d_out, int out_size, void* d_ws, size_t ws_size,
                              hipStream_t stream) {
  (void)n_in; (void)out_size; (void)ws_size;  // needs ws_size >= 212,992 B
  const float* O     = (const float*)d_in[0];
  const float* enc_w = (const float*)d_in[1];
  const float* enc_b = (const float*)d_in[2];
  const float* fc1_w = (const float*)d_in[3];
  const float* fc1_b = (const float*)d_in[4];
  const float* fc2_w = (const float*)d_in[5];
  const float* fc2_b = (const float*)d_in[6];
  const float* fc3_w = (const float*)d_in[7];
  const float* fc3_b = (const float*)d_in[8];
  const float* cl4_w = (const float*)d_in[9];
  const float* cl4_b = (const float*)d_in[10];
  const float* dec_w = (const float*)d_in[11];
  const float* dec_b = (const float*)d_in[12];
  unsigned short* wsb = (unsigned short*)d_ws;

  prep_weights<<<(WS_HALF + 255) / 256, 256, 0, stream>>>(enc_w, fc1_w, fc2_w, fc3_w,
                                                          cl4_w, dec_w, wsb);
  const int rows   = in_sizes[0] / 64;   // B*A = 262144
  const int blocks = rows / 64;          // 4096
  commnet_fwd<<<blocks, 256, 0, stream>>>(O, enc_b, fc1_b, fc2_b, fc3_b, cl4_b,
                                          dec_b, wsb, (float*)d_out);
}